// Round 8
// baseline (203.320 us; speedup 1.0000x reference)
//
#include <hip/hip_runtime.h>

#define N_TOKENS 32768
#define K_CODES  1024
#define DIM      256
#define BETA     0.25f

typedef unsigned long long u64;
typedef _Float16 half8 __attribute__((ext_vector_type(8)));
typedef float floatx4 __attribute__((ext_vector_type(4)));

// ---- init: wn[k]=||w_k||^2 (fp32 exact), counts=0, keys=+inf, w->hi/lo fp16 --
__global__ void init_kernel(const float* __restrict__ w, float* __restrict__ wn,
                            int* __restrict__ counts, u64* __restrict__ keys,
                            _Float16* __restrict__ whiG, _Float16* __restrict__ wloG) {
    int k = blockIdx.x;
    int lane = threadIdx.x;  // 64
    float4 v = *(const float4*)(w + (size_t)k * DIM + lane * 4);
    float vals[4] = {v.x, v.y, v.z, v.w};
    float s = 0.f;
    #pragma unroll
    for (int e = 0; e < 4; e++) {
        s += vals[e] * vals[e];
        _Float16 h = (_Float16)vals[e];
        whiG[k * DIM + lane * 4 + e] = h;
        wloG[k * DIM + lane * 4 + e] = (_Float16)(vals[e] - (float)h);
    }
    #pragma unroll
    for (int off = 32; off; off >>= 1) s += __shfl_down(s, off);
    if (lane == 0) { wn[k] = s; counts[k] = 0; }
    if (lane < 32) keys[k * 32 + lane] = ~0ull;   // 1024*32 = 32768 keys
}

// ---------------- argmin: fp16-split MFMA distance GEMM + atomicMin merge ----
// dot(z,w) = hi_z*hi_w + hi_z*lo_w + lo_z*hi_w  (lo*lo dropped, err ~1e-5).
// Round-8 = round-7 design, resubmitted (r7 died with zero counters; full
// audit found no fault vector, infra variance is the likely cause). Code-
// shape hardening only: lambdas w/ reference-array params -> macros.
// Design recap: wave tile 64x64 (acc[4][4]=64 AGPR) so the register file
// finally has ~40 regs of headroom for latency hiding (the 64x128 tile's
// 128-AGPR acc made r3/r5/r6 prefetches register-infeasible). Block 128 tok
// x 128 codes (4 waves), grid 8 code-eighths x 256 token-tiles.
// Per chunk: issue w(dt+1)+A(dt+1) globals -> cvt A(dt) (arrived last iter)
// -> 48 MFMA (setprio) -> ds_write w(dt+1) -> ONE barrier.
// z never in LDS (r5-verified exact); w dbuf 2x16 KB, 64B rows, XOR swizzle
// byte^=(row&3)<<4 (r5-measured 2x fewer conflicts than ZS=40 padding).
// Diagnostic: VGPR_Count should read ~190-230; ~130 = prefetch sunk again.
__global__ __launch_bounds__(256, 2) void argmin_kernel(
    const float* __restrict__ z, const _Float16* __restrict__ whiG,
    const _Float16* __restrict__ wloG, const float* __restrict__ wn,
    u64* __restrict__ keys)
{
    __shared__ __attribute__((aligned(16))) char wb[2][16384];  // [hi 8K | lo 8K]

    const int tid  = threadIdx.x;
    const int lane = tid & 63;
    const int wid  = tid >> 6;          // 0..3
    const int wm   = wid >> 1;          // token half (64)
    const int wq   = wid & 1;           // code half (64)
    const int t_   = blockIdx.x & 255;  // token tile (128 tokens)
    const int q8   = blockIdx.x >> 8;   // code eighth 0..7
    const int tok0  = t_ * 128;
    const int kbase = q8 * 128;

    // ||w||^2 for this thread's 4 epilogue columns -> registers
    float wnr[4];
    #pragma unroll
    for (int j = 0; j < 4; j++)
        wnr[j] = wn[kbase + wq * 64 + j * 16 + (lane & 15)];

    floatx4 acc[4][4];
    #pragma unroll
    for (int i = 0; i < 4; i++)
        #pragma unroll
        for (int j = 0; j < 4; j++)
            acc[i][j] = (floatx4){0.f, 0.f, 0.f, 0.f};

    // ---- w staging addressing: thread covers code row r0w, halves g0w..+15
    const int r0w = tid >> 1;             // 0..127
    const int g0w = (tid & 1) * 16;       // 0 or 16 (halves within 32-chunk)
    const int swzw = (r0w & 3) << 4;
    const int wbyte0 = r0w * 64 + ((2 * g0w) ^ swzw);
    const int wbyte1 = r0w * 64 + ((2 * g0w + 16) ^ swzw);
    const _Float16* whg = whiG + (size_t)(kbase + r0w) * DIM + g0w;
    const _Float16* wlg = wloG + (size_t)(kbase + r0w) * DIM + g0w;

    // ---- B fragment read addressing: row = wq*64 + j*16 + (lane&15)
    const int kg = lane >> 4;             // k-group 0..3
    const int rb = (wq * 64 + (lane & 15)) * 64 + ((kg * 16) ^ ((lane & 3) << 4));

    // ---- A direct-global base: z row tok0 + wm*64 + i*16 + (lane&15)
    const float* zA = z + (size_t)(tok0 + wm * 64 + (lane & 15)) * DIM + kg * 8;

    float4 zrA[8], zrB[8];                // A raw ping-pong (32+32 regs)
    half8 wha, whb, wla, wlb;             // w in-flight regs (16)

#define LOADW(dtn) do { \
    wha = *(const half8*)(whg + (dtn) * 32); \
    whb = *(const half8*)(whg + (dtn) * 32 + 8); \
    wla = *(const half8*)(wlg + (dtn) * 32); \
    wlb = *(const half8*)(wlg + (dtn) * 32 + 8); \
} while (0)

#define WRITEW(b) do { \
    *(half8*)&wb[b][wbyte0] = wha; \
    *(half8*)&wb[b][wbyte1] = whb; \
    *(half8*)&wb[b][8192 + wbyte0] = wla; \
    *(half8*)&wb[b][8192 + wbyte1] = wlb; \
} while (0)

#define LOADA(dtn, zr) do { \
    const float* p0 = zA + (dtn) * 32; \
    zr[0] = *(const float4*)p0;                      zr[1] = *(const float4*)(p0 + 4); \
    const float* p1 = zA + (size_t)16 * DIM + (dtn) * 32; \
    zr[2] = *(const float4*)p1;                      zr[3] = *(const float4*)(p1 + 4); \
    const float* p2 = zA + (size_t)32 * DIM + (dtn) * 32; \
    zr[4] = *(const float4*)p2;                      zr[5] = *(const float4*)(p2 + 4); \
    const float* p3 = zA + (size_t)48 * DIM + (dtn) * 32; \
    zr[6] = *(const float4*)p3;                      zr[7] = *(const float4*)(p3 + 4); \
} while (0)

#define STEP(dt, cur, zc, zl) do { \
    if ((dt) < 7) { LOADW((dt) + 1); LOADA((dt) + 1, zl); } \
    half8 ah[4], al[4]; \
    _Pragma("unroll") \
    for (int i = 0; i < 4; i++) { \
        float vals[8] = {zc[2*i].x, zc[2*i].y, zc[2*i].z, zc[2*i].w, \
                         zc[2*i+1].x, zc[2*i+1].y, zc[2*i+1].z, zc[2*i+1].w}; \
        _Pragma("unroll") \
        for (int e = 0; e < 8; e++) { \
            _Float16 h = (_Float16)vals[e]; \
            ah[i][e] = h; \
            al[i][e] = (_Float16)(vals[e] - (float)h); \
        } \
    } \
    __builtin_amdgcn_s_setprio(1); \
    _Pragma("unroll") \
    for (int j = 0; j < 4; j++) { \
        half8 bh = *(const half8*)&wb[cur][rb + j * 1024]; \
        half8 bl = *(const half8*)&wb[cur][rb + j * 1024 + 8192]; \
        _Pragma("unroll") \
        for (int i = 0; i < 4; i++) { \
            acc[i][j] = __builtin_amdgcn_mfma_f32_16x16x32_f16(ah[i], bh, acc[i][j], 0, 0, 0); \
            acc[i][j] = __builtin_amdgcn_mfma_f32_16x16x32_f16(ah[i], bl, acc[i][j], 0, 0, 0); \
            acc[i][j] = __builtin_amdgcn_mfma_f32_16x16x32_f16(al[i], bh, acc[i][j], 0, 0, 0); \
        } \
    } \
    __builtin_amdgcn_s_setprio(0); \
    if ((dt) < 7) WRITEW((cur) ^ 1); \
    __syncthreads(); \
} while (0)

    // prologue: w(0) + A(0) issued, w(0) staged, barrier
    LOADW(0);
    LOADA(0, zrA);
    WRITEW(0);
    __syncthreads();

    STEP(0, 0, zrA, zrB);
    STEP(1, 1, zrB, zrA);
    STEP(2, 0, zrA, zrB);
    STEP(3, 1, zrB, zrA);
    STEP(4, 0, zrA, zrB);
    STEP(5, 1, zrB, zrA);
    STEP(6, 0, zrA, zrB);
    STEP(7, 1, zrB, zrA);

#undef LOADW
#undef WRITEW
#undef LOADA
#undef STEP

    // epilogue: dist = wn[code] - 2*dot (||z||^2 constant per row).
    // C layout: col(code) = lane&15, row(token) = (lane>>4)*4 + reg.
    #pragma unroll
    for (int i = 0; i < 4; i++) {
        #pragma unroll
        for (int r = 0; r < 4; r++) {
            float bv = 3.4e38f; int bi = 0;
            #pragma unroll
            for (int j = 0; j < 4; j++) {
                int cl = wq * 64 + j * 16 + (lane & 15);
                float dist = wnr[j] - 2.0f * acc[i][j][r];
                if (dist < bv) { bv = dist; bi = kbase + cl; }
            }
            unsigned uu = __float_as_uint(bv);
            unsigned ss = (uu & 0x80000000u) ? ~uu : (uu | 0x80000000u);
            u64 key = ((u64)ss << 32) | (unsigned)bi;
            #pragma unroll
            for (int m = 1; m < 16; m <<= 1) {
                u64 o = __shfl_xor(key, m);
                if (o < key) key = o;
            }
            if ((lane & 15) == 0) {
                int token = tok0 + wm * 64 + i * 16 + (lane >> 4) * 4 + r;
                atomicMin(&keys[token], key);
            }
        }
    }
}

// ---------------- gather + commitment loss + idx/counts ----------------
// wave (64 lanes) = one token (64 float4). 8192 waves x 4 iters.
// k masked to 10 bits: valid keys always carry code < 1024; converts any
// upstream failure into a clean numeric mismatch instead of a wild gather
// -> memory fault -> dead container (round-1/2 lesson).
__global__ void gather_loss_kernel(const float* __restrict__ z,
                                   const float* __restrict__ w,
                                   const u64* __restrict__ keys,
                                   float* __restrict__ zq_out,
                                   float* __restrict__ idxf,
                                   int* __restrict__ counts,
                                   float* __restrict__ partials)
{
    __shared__ float red[4];
    int tid = threadIdx.x;
    int lane = tid & 63;
    int wid = blockIdx.x * 4 + (tid >> 6);   // 0..8191
    float s = 0.0f;
    #pragma unroll
    for (int it = 0; it < 4; it++) {
        int tok = wid + it * 8192;
        u64 key = 0;
        if (lane == 0) key = keys[tok];
        key = __shfl(key, 0);
        int k = (int)(key & (u64)(K_CODES - 1));
        float4 wv = *(const float4*)(w + (size_t)k * DIM + lane * 4);
        float4 zv = *(const float4*)(z + (size_t)tok * DIM + lane * 4);
        *(float4*)(zq_out + (size_t)tok * DIM + lane * 4) = wv;
        float dx = wv.x - zv.x, dy = wv.y - zv.y, dz = wv.z - zv.z, dw = wv.w - zv.w;
        s += dx * dx + dy * dy + dz * dz + dw * dw;
        if (lane == 0) {
            idxf[tok] = (float)k;
            atomicAdd(&counts[k], 1);
        }
    }
    #pragma unroll
    for (int off = 32; off; off >>= 1) s += __shfl_down(s, off);
    if (lane == 0) red[tid >> 6] = s;
    __syncthreads();
    if (tid == 0)
        partials[blockIdx.x] = red[0] + red[1] + red[2] + red[3];
}

// ---------------- perplexity + loss finalize ----------------
__global__ void finalize_kernel(const int* __restrict__ counts,
                                const float* __restrict__ partials,
                                float* __restrict__ loss_out,
                                float* __restrict__ ppl_out)
{
    __shared__ float redE[16], redL[16];
    int tid = threadIdx.x;  // 1024
    float e = (float)counts[tid] * (1.0f / (float)N_TOKENS);
    float t = -e * logf(e + 1e-10f);
    float p = partials[tid] + partials[tid + 1024];
    #pragma unroll
    for (int off = 32; off; off >>= 1) {
        t += __shfl_down(t, off);
        p += __shfl_down(p, off);
    }
    if ((tid & 63) == 0) { redE[tid >> 6] = t; redL[tid >> 6] = p; }
    __syncthreads();
    if (tid == 0) {
        float se = 0.0f, sl = 0.0f;
        #pragma unroll
        for (int i = 0; i < 16; i++) { se += redE[i]; sl += redL[i]; }
        *ppl_out = expf(se);
        *loss_out = BETA * sl / (float)((size_t)N_TOKENS * DIM);
    }
}

extern "C" void kernel_launch(void* const* d_in, const int* in_sizes, int n_in,
                              void* d_out, int out_size, void* d_ws, size_t ws_size,
                              hipStream_t stream) {
    const float* z = (const float*)d_in[0];
    const float* w = (const float*)d_in[1];
    float* out = (float*)d_out;

    // d_out layout (float): [0]=loss, [1..NT*D]=z_q_st, [..]=indices(float), [last]=perplexity
    float* loss_out = out;
    float* zq_out   = out + 1;
    float* idxf     = out + 1 + (size_t)N_TOKENS * DIM;
    float* ppl_out  = out + (out_size - 1);

    // ws layout: wn f32[1024] | counts i32[1024] | partials f32[2048]
    //            | keys u64[32768] @ byte 16384 | whiG/wloG fp16[1024*256] @ 278528
    float* wn       = (float*)d_ws;
    int*   counts   = (int*)d_ws + 1024;
    float* partials = (float*)d_ws + 2048;
    u64*   keys     = (u64*)((char*)d_ws + 16384);
    _Float16* whiG  = (_Float16*)((char*)d_ws + 16384 + (size_t)N_TOKENS * 8);
    _Float16* wloG  = whiG + (size_t)K_CODES * DIM;

    init_kernel<<<K_CODES, 64, 0, stream>>>(w, wn, counts, keys, whiG, wloG);
    argmin_kernel<<<8 * 256, 256, 0, stream>>>(z, whiG, wloG, wn, keys);
    gather_loss_kernel<<<2048, 256, 0, stream>>>(z, w, keys, zq_out, idxf, counts, partials);
    finalize_kernel<<<1, 1024, 0, stream>>>(counts, partials, loss_out, ppl_out);
}

// Round 9
// 177.768 us; speedup vs baseline: 1.1437x; 1.1437x over previous
//
#include <hip/hip_runtime.h>

#define N_TOKENS 32768
#define K_CODES  1024
#define DIM      256
#define BETA     0.25f

typedef unsigned long long u64;
typedef _Float16 half8 __attribute__((ext_vector_type(8)));
typedef float floatx4 __attribute__((ext_vector_type(4)));

// ---- init: wn[k]=||w_k||^2 (fp32 exact), counts=0, keys=+inf, w->hi/lo fp16 --
__global__ void init_kernel(const float* __restrict__ w, float* __restrict__ wn,
                            int* __restrict__ counts, u64* __restrict__ keys,
                            _Float16* __restrict__ whiG, _Float16* __restrict__ wloG) {
    int k = blockIdx.x;
    int lane = threadIdx.x;  // 64
    float4 v = *(const float4*)(w + (size_t)k * DIM + lane * 4);
    float vals[4] = {v.x, v.y, v.z, v.w};
    float s = 0.f;
    #pragma unroll
    for (int e = 0; e < 4; e++) {
        s += vals[e] * vals[e];
        _Float16 h = (_Float16)vals[e];
        whiG[k * DIM + lane * 4 + e] = h;
        wloG[k * DIM + lane * 4 + e] = (_Float16)(vals[e] - (float)h);
    }
    #pragma unroll
    for (int off = 32; off; off >>= 1) s += __shfl_down(s, off);
    if (lane == 0) { wn[k] = s; counts[k] = 0; }
    if (lane < 32) keys[k * 32 + lane] = ~0ull;   // 1024*32 = 32768 keys
}

// ---------------- argmin: fp16-split MFMA distance GEMM + atomicMin merge ----
// dot(z,w) = hi_z*hi_w + hi_z*lo_w + lo_z*hi_w  (lo*lo dropped, err ~1e-5).
// ROUND-9: the r4 schedule VERBATIM (serial stage between two barriers ->
// frag reads -> MFMA w/ setprio; ZS=40 rows; z+w both in LDS), but sized for
// 4 BLOCKS/CU instead of 2. Eight rounds of evidence: hipcc sinks every
// source-level prefetch regardless of register headroom (r3/r5/r6/r8 -- r8
// had 104 VGPR and still sank), so the ONLY working latency-hiding on this
// structure is cross-block overlap. Doubling co-resident blocks doubles the
// independent MFMA phases covering each serial staging phase.
//  - block 128 tok x 128 codes, 4 waves, wave tile 64x64 (acc[4][4]=64 AGPR)
//  - LDS 40960 B: 4 x 40960 = exactly the 160 KiB pool -> 4 blocks/CU
//  - __launch_bounds__(256,4): unified reg cap 128/thread (64 acc + ~60 VGPR)
//  - grid 8 code-eighths x 256 token-tiles, q8 in LOW bits (blocks sharing a
//    z tile are dispatch-adjacent for L2/L3 locality)
// Diagnostic: OccupancyPercent ~35-42% = success; ~20% = blocked, wash.
__global__ __launch_bounds__(256, 4) void argmin_kernel(
    const float* __restrict__ z, const _Float16* __restrict__ whiG,
    const _Float16* __restrict__ wloG, const float* __restrict__ wn,
    u64* __restrict__ keys)
{
    constexpr int ZS = 40;   // halves per row (80 B, 16-B aligned)
    __shared__ _Float16 zhi[128 * ZS], zlo[128 * ZS];
    __shared__ _Float16 whi[128 * ZS], wlo[128 * ZS];

    const int tid  = threadIdx.x;
    const int lane = tid & 63;
    const int wid  = tid >> 6;          // 0..3
    const int wm   = wid >> 1;          // token half (64)
    const int wq   = wid & 1;           // code half (64)
    const int q8   = blockIdx.x & 7;    // code eighth 0..7
    const int t_   = blockIdx.x >> 3;   // token tile 0..255
    const int tok0  = t_ * 128;
    const int kbase = q8 * 128;

    // ||w||^2 for this thread's 4 epilogue columns -> registers
    float wnr[4];
    #pragma unroll
    for (int j = 0; j < 4; j++)
        wnr[j] = wn[kbase + wq * 64 + j * 16 + (lane & 15)];

    floatx4 acc[4][4];
    #pragma unroll
    for (int i = 0; i < 4; i++)
        #pragma unroll
        for (int j = 0; j < 4; j++)
            acc[i][j] = (floatx4){0.f, 0.f, 0.f, 0.f};

    const int r0 = tid >> 2;   // staging row (0..63)
    const int g0 = tid & 3;    // 8-half group within 32-chunk

    for (int dt = 0; dt < 8; ++dt) {
        const int d0 = dt * 32;
        __syncthreads();   // previous chunk's fragment reads done

        // stage z chunk (128 tok x 32 d): fp32 -> (hi,lo) fp16
        #pragma unroll
        for (int s = 0; s < 2; s++) {
            int t = r0 + s * 64;
            const float* p = z + (size_t)(tok0 + t) * DIM + d0 + g0 * 8;
            float4 a = *(const float4*)p;
            float4 b = *(const float4*)(p + 4);
            float vals[8] = {a.x, a.y, a.z, a.w, b.x, b.y, b.z, b.w};
            half8 hv, lv;
            #pragma unroll
            for (int e = 0; e < 8; e++) {
                _Float16 h = (_Float16)vals[e];
                hv[e] = h;
                lv[e] = (_Float16)(vals[e] - (float)h);
            }
            *(half8*)&zhi[t * ZS + g0 * 8] = hv;
            *(half8*)&zlo[t * ZS + g0 * 8] = lv;
        }
        // stage w chunk (128 codes x 32 d): pre-split fp16, pure copy
        #pragma unroll
        for (int s = 0; s < 2; s++) {
            int t = r0 + s * 64;
            size_t goff = (size_t)(kbase + t) * DIM + d0 + g0 * 8;
            *(half8*)&whi[t * ZS + g0 * 8] = *(const half8*)&whiG[goff];
            *(half8*)&wlo[t * ZS + g0 * 8] = *(const half8*)&wloG[goff];
        }
        __syncthreads();

        // fragments: A[m=lane&15][k=(lane>>4)*8+e], B[k][n=lane&15]
        const int koff = (lane >> 4) * 8;
        half8 ah[4], al[4];
        #pragma unroll
        for (int i = 0; i < 4; i++) {
            int off = (wm * 64 + i * 16 + (lane & 15)) * ZS + koff;
            ah[i] = *(const half8*)&zhi[off];
            al[i] = *(const half8*)&zlo[off];
        }
        __builtin_amdgcn_s_setprio(1);   // T5: favor MFMA-phase waves
        #pragma unroll
        for (int j = 0; j < 4; j++) {
            int off = (wq * 64 + j * 16 + (lane & 15)) * ZS + koff;
            half8 bh = *(const half8*)&whi[off];
            half8 bl = *(const half8*)&wlo[off];
            #pragma unroll
            for (int i = 0; i < 4; i++) {
                acc[i][j] = __builtin_amdgcn_mfma_f32_16x16x32_f16(ah[i], bh, acc[i][j], 0, 0, 0);
                acc[i][j] = __builtin_amdgcn_mfma_f32_16x16x32_f16(ah[i], bl, acc[i][j], 0, 0, 0);
                acc[i][j] = __builtin_amdgcn_mfma_f32_16x16x32_f16(al[i], bh, acc[i][j], 0, 0, 0);
            }
        }
        __builtin_amdgcn_s_setprio(0);
    }

    // epilogue: dist = wn[code] - 2*dot (||z||^2 constant per row).
    // C layout: col(code) = lane&15, row(token) = (lane>>4)*4 + reg.
    #pragma unroll
    for (int i = 0; i < 4; i++) {
        #pragma unroll
        for (int r = 0; r < 4; r++) {
            float bv = 3.4e38f; int bi = 0;
            #pragma unroll
            for (int j = 0; j < 4; j++) {
                int cl = wq * 64 + j * 16 + (lane & 15);
                float dist = wnr[j] - 2.0f * acc[i][j][r];
                if (dist < bv) { bv = dist; bi = kbase + cl; }
            }
            unsigned uu = __float_as_uint(bv);
            unsigned ss = (uu & 0x80000000u) ? ~uu : (uu | 0x80000000u);
            u64 key = ((u64)ss << 32) | (unsigned)bi;
            #pragma unroll
            for (int m = 1; m < 16; m <<= 1) {
                u64 o = __shfl_xor(key, m);
                if (o < key) key = o;
            }
            if ((lane & 15) == 0) {
                int token = tok0 + wm * 64 + i * 16 + (lane >> 4) * 4 + r;
                atomicMin(&keys[token], key);
            }
        }
    }
}

// ---------------- gather + commitment loss + idx/counts ----------------
// wave (64 lanes) = one token (64 float4). 8192 waves x 4 iters.
// k masked to 10 bits: valid keys always carry code < 1024; converts any
// upstream failure into a clean numeric mismatch instead of a wild gather
// -> memory fault -> dead container (round-1/2 lesson).
__global__ void gather_loss_kernel(const float* __restrict__ z,
                                   const float* __restrict__ w,
                                   const u64* __restrict__ keys,
                                   float* __restrict__ zq_out,
                                   float* __restrict__ idxf,
                                   int* __restrict__ counts,
                                   float* __restrict__ partials)
{
    __shared__ float red[4];
    int tid = threadIdx.x;
    int lane = tid & 63;
    int wid = blockIdx.x * 4 + (tid >> 6);   // 0..8191
    float s = 0.0f;
    #pragma unroll
    for (int it = 0; it < 4; it++) {
        int tok = wid + it * 8192;
        u64 key = 0;
        if (lane == 0) key = keys[tok];
        key = __shfl(key, 0);
        int k = (int)(key & (u64)(K_CODES - 1));
        float4 wv = *(const float4*)(w + (size_t)k * DIM + lane * 4);
        float4 zv = *(const float4*)(z + (size_t)tok * DIM + lane * 4);
        *(float4*)(zq_out + (size_t)tok * DIM + lane * 4) = wv;
        float dx = wv.x - zv.x, dy = wv.y - zv.y, dz = wv.z - zv.z, dw = wv.w - zv.w;
        s += dx * dx + dy * dy + dz * dz + dw * dw;
        if (lane == 0) {
            idxf[tok] = (float)k;
            atomicAdd(&counts[k], 1);
        }
    }
    #pragma unroll
    for (int off = 32; off; off >>= 1) s += __shfl_down(s, off);
    if (lane == 0) red[tid >> 6] = s;
    __syncthreads();
    if (tid == 0)
        partials[blockIdx.x] = red[0] + red[1] + red[2] + red[3];
}

// ---------------- perplexity + loss finalize ----------------
__global__ void finalize_kernel(const int* __restrict__ counts,
                                const float* __restrict__ partials,
                                float* __restrict__ loss_out,
                                float* __restrict__ ppl_out)
{
    __shared__ float redE[16], redL[16];
    int tid = threadIdx.x;  // 1024
    float e = (float)counts[tid] * (1.0f / (float)N_TOKENS);
    float t = -e * logf(e + 1e-10f);
    float p = partials[tid] + partials[tid + 1024];
    #pragma unroll
    for (int off = 32; off; off >>= 1) {
        t += __shfl_down(t, off);
        p += __shfl_down(p, off);
    }
    if ((tid & 63) == 0) { redE[tid >> 6] = t; redL[tid >> 6] = p; }
    __syncthreads();
    if (tid == 0) {
        float se = 0.0f, sl = 0.0f;
        #pragma unroll
        for (int i = 0; i < 16; i++) { se += redE[i]; sl += redL[i]; }
        *ppl_out = expf(se);
        *loss_out = BETA * sl / (float)((size_t)N_TOKENS * DIM);
    }
}

extern "C" void kernel_launch(void* const* d_in, const int* in_sizes, int n_in,
                              void* d_out, int out_size, void* d_ws, size_t ws_size,
                              hipStream_t stream) {
    const float* z = (const float*)d_in[0];
    const float* w = (const float*)d_in[1];
    float* out = (float*)d_out;

    // d_out layout (float): [0]=loss, [1..NT*D]=z_q_st, [..]=indices(float), [last]=perplexity
    float* loss_out = out;
    float* zq_out   = out + 1;
    float* idxf     = out + 1 + (size_t)N_TOKENS * DIM;
    float* ppl_out  = out + (out_size - 1);

    // ws layout: wn f32[1024] | counts i32[1024] | partials f32[2048]
    //            | keys u64[32768] @ byte 16384 | whiG/wloG fp16[1024*256] @ 278528
    float* wn       = (float*)d_ws;
    int*   counts   = (int*)d_ws + 1024;
    float* partials = (float*)d_ws + 2048;
    u64*   keys     = (u64*)((char*)d_ws + 16384);
    _Float16* whiG  = (_Float16*)((char*)d_ws + 16384 + (size_t)N_TOKENS * 8);
    _Float16* wloG  = whiG + (size_t)K_CODES * DIM;

    init_kernel<<<K_CODES, 64, 0, stream>>>(w, wn, counts, keys, whiG, wloG);
    argmin_kernel<<<8 * 256, 256, 0, stream>>>(z, whiG, wloG, wn, keys);
    gather_loss_kernel<<<2048, 256, 0, stream>>>(z, w, keys, zq_out, idxf, counts, partials);
    finalize_kernel<<<1, 1024, 0, stream>>>(counts, partials, loss_out, ppl_out);
}

// Round 10
// 170.436 us; speedup vs baseline: 1.1929x; 1.0430x over previous
//
#include <hip/hip_runtime.h>

#define N_TOKENS 32768
#define K_CODES  1024
#define DIM      256
#define BETA     0.25f

typedef unsigned long long u64;
typedef _Float16 half8 __attribute__((ext_vector_type(8)));
typedef float floatx4 __attribute__((ext_vector_type(4)));

// ---- init: wn[k]=||w_k||^2 (fp32 exact), counts=0, keys=+inf, w->hi/lo fp16 --
__global__ void init_kernel(const float* __restrict__ w, float* __restrict__ wn,
                            int* __restrict__ counts, u64* __restrict__ keys,
                            _Float16* __restrict__ whiG, _Float16* __restrict__ wloG) {
    int k = blockIdx.x;
    int lane = threadIdx.x;  // 64
    float4 v = *(const float4*)(w + (size_t)k * DIM + lane * 4);
    float vals[4] = {v.x, v.y, v.z, v.w};
    float s = 0.f;
    #pragma unroll
    for (int e = 0; e < 4; e++) {
        s += vals[e] * vals[e];
        _Float16 h = (_Float16)vals[e];
        whiG[k * DIM + lane * 4 + e] = h;
        wloG[k * DIM + lane * 4 + e] = (_Float16)(vals[e] - (float)h);
    }
    #pragma unroll
    for (int off = 32; off; off >>= 1) s += __shfl_down(s, off);
    if (lane == 0) { wn[k] = s; counts[k] = 0; }
    if (lane < 32) keys[k * 32 + lane] = ~0ull;   // 1024*32 = 32768 keys
}

// ---------------- argmin: fp16-split MFMA distance GEMM + atomicMin merge ----
// dot(z,w) = hi_z*hi_w + hi_z*lo_w + lo_z*hi_w  (lo*lo dropped, err ~1e-5).
// ROUND-10 = round-9 kernel with ONE fix: blockIdx decode back to t_ in the
// LOW bits. r9's q8-low mapping put each code-eighth on one XCD (round-robin
// dispatch: XCD x got exactly q8==x), so every XCD streamed the whole 32 MB
// z through its private 4 MB L2: FETCH 33->132 MB, argmin 62.5->78 us,
// traffic-bound. With t_ low (r4's mapping) each XCD owns ~32 token tiles
// (z working set ~4 MB = L2 size) and the w eighth (128 KB) is L2-resident.
// Kept from r9 (both verified): 4 blocks/CU occupancy (Occupancy 19.5->40%,
// VGPR 64, LDS 40960 x 4 = the full 160 KiB pool) and the 64x64 wave tile.
// r4 schedule otherwise verbatim: serial stage between two barriers -> frag
// reads -> MFMA w/ setprio; ZS=40 rows; cross-block overlap hides latency
// (hipcc sinks all source-level prefetch: r3/r5/r6/r8 evidence).
// Diagnostic: FETCH_SIZE ~35-45 MB = mapping model confirmed; >100 MB = wrong.
__global__ __launch_bounds__(256, 4) void argmin_kernel(
    const float* __restrict__ z, const _Float16* __restrict__ whiG,
    const _Float16* __restrict__ wloG, const float* __restrict__ wn,
    u64* __restrict__ keys)
{
    constexpr int ZS = 40;   // halves per row (80 B, 16-B aligned)
    __shared__ _Float16 zhi[128 * ZS], zlo[128 * ZS];
    __shared__ _Float16 whi[128 * ZS], wlo[128 * ZS];

    const int tid  = threadIdx.x;
    const int lane = tid & 63;
    const int wid  = tid >> 6;          // 0..3
    const int wm   = wid >> 1;          // token half (64)
    const int wq   = wid & 1;           // code half (64)
    const int t_   = blockIdx.x & 255;  // token tile 0..255  (LOW bits: XCD locality)
    const int q8   = blockIdx.x >> 8;   // code eighth 0..7
    const int tok0  = t_ * 128;
    const int kbase = q8 * 128;

    // ||w||^2 for this thread's 4 epilogue columns -> registers
    float wnr[4];
    #pragma unroll
    for (int j = 0; j < 4; j++)
        wnr[j] = wn[kbase + wq * 64 + j * 16 + (lane & 15)];

    floatx4 acc[4][4];
    #pragma unroll
    for (int i = 0; i < 4; i++)
        #pragma unroll
        for (int j = 0; j < 4; j++)
            acc[i][j] = (floatx4){0.f, 0.f, 0.f, 0.f};

    const int r0 = tid >> 2;   // staging row (0..63)
    const int g0 = tid & 3;    // 8-half group within 32-chunk

    for (int dt = 0; dt < 8; ++dt) {
        const int d0 = dt * 32;
        __syncthreads();   // previous chunk's fragment reads done

        // stage z chunk (128 tok x 32 d): fp32 -> (hi,lo) fp16
        #pragma unroll
        for (int s = 0; s < 2; s++) {
            int t = r0 + s * 64;
            const float* p = z + (size_t)(tok0 + t) * DIM + d0 + g0 * 8;
            float4 a = *(const float4*)p;
            float4 b = *(const float4*)(p + 4);
            float vals[8] = {a.x, a.y, a.z, a.w, b.x, b.y, b.z, b.w};
            half8 hv, lv;
            #pragma unroll
            for (int e = 0; e < 8; e++) {
                _Float16 h = (_Float16)vals[e];
                hv[e] = h;
                lv[e] = (_Float16)(vals[e] - (float)h);
            }
            *(half8*)&zhi[t * ZS + g0 * 8] = hv;
            *(half8*)&zlo[t * ZS + g0 * 8] = lv;
        }
        // stage w chunk (128 codes x 32 d): pre-split fp16, pure copy
        #pragma unroll
        for (int s = 0; s < 2; s++) {
            int t = r0 + s * 64;
            size_t goff = (size_t)(kbase + t) * DIM + d0 + g0 * 8;
            *(half8*)&whi[t * ZS + g0 * 8] = *(const half8*)&whiG[goff];
            *(half8*)&wlo[t * ZS + g0 * 8] = *(const half8*)&wloG[goff];
        }
        __syncthreads();

        // fragments: A[m=lane&15][k=(lane>>4)*8+e], B[k][n=lane&15]
        const int koff = (lane >> 4) * 8;
        half8 ah[4], al[4];
        #pragma unroll
        for (int i = 0; i < 4; i++) {
            int off = (wm * 64 + i * 16 + (lane & 15)) * ZS + koff;
            ah[i] = *(const half8*)&zhi[off];
            al[i] = *(const half8*)&zlo[off];
        }
        __builtin_amdgcn_s_setprio(1);   // T5: favor MFMA-phase waves
        #pragma unroll
        for (int j = 0; j < 4; j++) {
            int off = (wq * 64 + j * 16 + (lane & 15)) * ZS + koff;
            half8 bh = *(const half8*)&whi[off];
            half8 bl = *(const half8*)&wlo[off];
            #pragma unroll
            for (int i = 0; i < 4; i++) {
                acc[i][j] = __builtin_amdgcn_mfma_f32_16x16x32_f16(ah[i], bh, acc[i][j], 0, 0, 0);
                acc[i][j] = __builtin_amdgcn_mfma_f32_16x16x32_f16(ah[i], bl, acc[i][j], 0, 0, 0);
                acc[i][j] = __builtin_amdgcn_mfma_f32_16x16x32_f16(al[i], bh, acc[i][j], 0, 0, 0);
            }
        }
        __builtin_amdgcn_s_setprio(0);
    }

    // epilogue: dist = wn[code] - 2*dot (||z||^2 constant per row).
    // C layout: col(code) = lane&15, row(token) = (lane>>4)*4 + reg.
    #pragma unroll
    for (int i = 0; i < 4; i++) {
        #pragma unroll
        for (int r = 0; r < 4; r++) {
            float bv = 3.4e38f; int bi = 0;
            #pragma unroll
            for (int j = 0; j < 4; j++) {
                int cl = wq * 64 + j * 16 + (lane & 15);
                float dist = wnr[j] - 2.0f * acc[i][j][r];
                if (dist < bv) { bv = dist; bi = kbase + cl; }
            }
            unsigned uu = __float_as_uint(bv);
            unsigned ss = (uu & 0x80000000u) ? ~uu : (uu | 0x80000000u);
            u64 key = ((u64)ss << 32) | (unsigned)bi;
            #pragma unroll
            for (int m = 1; m < 16; m <<= 1) {
                u64 o = __shfl_xor(key, m);
                if (o < key) key = o;
            }
            if ((lane & 15) == 0) {
                int token = tok0 + wm * 64 + i * 16 + (lane >> 4) * 4 + r;
                atomicMin(&keys[token], key);
            }
        }
    }
}

// ---------------- gather + commitment loss + idx/counts ----------------
// wave (64 lanes) = one token (64 float4). 8192 waves x 4 iters.
// k masked to 10 bits: valid keys always carry code < 1024; converts any
// upstream failure into a clean numeric mismatch instead of a wild gather
// -> memory fault -> dead container (round-1/2 lesson).
__global__ void gather_loss_kernel(const float* __restrict__ z,
                                   const float* __restrict__ w,
                                   const u64* __restrict__ keys,
                                   float* __restrict__ zq_out,
                                   float* __restrict__ idxf,
                                   int* __restrict__ counts,
                                   float* __restrict__ partials)
{
    __shared__ float red[4];
    int tid = threadIdx.x;
    int lane = tid & 63;
    int wid = blockIdx.x * 4 + (tid >> 6);   // 0..8191
    float s = 0.0f;
    #pragma unroll
    for (int it = 0; it < 4; it++) {
        int tok = wid + it * 8192;
        u64 key = 0;
        if (lane == 0) key = keys[tok];
        key = __shfl(key, 0);
        int k = (int)(key & (u64)(K_CODES - 1));
        float4 wv = *(const float4*)(w + (size_t)k * DIM + lane * 4);
        float4 zv = *(const float4*)(z + (size_t)tok * DIM + lane * 4);
        *(float4*)(zq_out + (size_t)tok * DIM + lane * 4) = wv;
        float dx = wv.x - zv.x, dy = wv.y - zv.y, dz = wv.z - zv.z, dw = wv.w - zv.w;
        s += dx * dx + dy * dy + dz * dz + dw * dw;
        if (lane == 0) {
            idxf[tok] = (float)k;
            atomicAdd(&counts[k], 1);
        }
    }
    #pragma unroll
    for (int off = 32; off; off >>= 1) s += __shfl_down(s, off);
    if (lane == 0) red[tid >> 6] = s;
    __syncthreads();
    if (tid == 0)
        partials[blockIdx.x] = red[0] + red[1] + red[2] + red[3];
}

// ---------------- perplexity + loss finalize ----------------
__global__ void finalize_kernel(const int* __restrict__ counts,
                                const float* __restrict__ partials,
                                float* __restrict__ loss_out,
                                float* __restrict__ ppl_out)
{
    __shared__ float redE[16], redL[16];
    int tid = threadIdx.x;  // 1024
    float e = (float)counts[tid] * (1.0f / (float)N_TOKENS);
    float t = -e * logf(e + 1e-10f);
    float p = partials[tid] + partials[tid + 1024];
    #pragma unroll
    for (int off = 32; off; off >>= 1) {
        t += __shfl_down(t, off);
        p += __shfl_down(p, off);
    }
    if ((tid & 63) == 0) { redE[tid >> 6] = t; redL[tid >> 6] = p; }
    __syncthreads();
    if (tid == 0) {
        float se = 0.0f, sl = 0.0f;
        #pragma unroll
        for (int i = 0; i < 16; i++) { se += redE[i]; sl += redL[i]; }
        *ppl_out = expf(se);
        *loss_out = BETA * sl / (float)((size_t)N_TOKENS * DIM);
    }
}

extern "C" void kernel_launch(void* const* d_in, const int* in_sizes, int n_in,
                              void* d_out, int out_size, void* d_ws, size_t ws_size,
                              hipStream_t stream) {
    const float* z = (const float*)d_in[0];
    const float* w = (const float*)d_in[1];
    float* out = (float*)d_out;

    // d_out layout (float): [0]=loss, [1..NT*D]=z_q_st, [..]=indices(float), [last]=perplexity
    float* loss_out = out;
    float* zq_out   = out + 1;
    float* idxf     = out + 1 + (size_t)N_TOKENS * DIM;
    float* ppl_out  = out + (out_size - 1);

    // ws layout: wn f32[1024] | counts i32[1024] | partials f32[2048]
    //            | keys u64[32768] @ byte 16384 | whiG/wloG fp16[1024*256] @ 278528
    float* wn       = (float*)d_ws;
    int*   counts   = (int*)d_ws + 1024;
    float* partials = (float*)d_ws + 2048;
    u64*   keys     = (u64*)((char*)d_ws + 16384);
    _Float16* whiG  = (_Float16*)((char*)d_ws + 16384 + (size_t)N_TOKENS * 8);
    _Float16* wloG  = whiG + (size_t)K_CODES * DIM;

    init_kernel<<<K_CODES, 64, 0, stream>>>(w, wn, counts, keys, whiG, wloG);
    argmin_kernel<<<8 * 256, 256, 0, stream>>>(z, whiG, wloG, wn, keys);
    gather_loss_kernel<<<2048, 256, 0, stream>>>(z, w, keys, zq_out, idxf, counts, partials);
    finalize_kernel<<<1, 1024, 0, stream>>>(counts, partials, loss_out, ppl_out);
}

// Round 11
// 168.028 us; speedup vs baseline: 1.2100x; 1.0143x over previous
//
#include <hip/hip_runtime.h>

#define N_TOKENS 32768
#define K_CODES  1024
#define DIM      256
#define BETA     0.25f

typedef unsigned long long u64;
typedef _Float16 half8 __attribute__((ext_vector_type(8)));
typedef _Float16 half4 __attribute__((ext_vector_type(4)));
typedef float floatx4 __attribute__((ext_vector_type(4)));

// global -> LDS direct DMA, 16 B/lane: dest = wave-uniform base + lane*16.
__device__ __forceinline__ void glds16(const void* g, void* l) {
    __builtin_amdgcn_global_load_lds(
        (const __attribute__((address_space(1))) void*)g,
        (__attribute__((address_space(3))) void*)l, 16, 0, 0);
}

// ---- init: wn, counts, keys, and the w DMA image.
// Image: per (q8,dt) a 16 KB chunk = [128 rows][64 B] hi (8 KB) then lo,
// with the read-side XOR swizzle byte^=(row&3)<<4 PRE-APPLIED (rule 21:
// DMA writes linearly, so the global image carries the swizzle; ds_reads
// apply the same XOR -> both-sides-or-neither satisfied by imaging).
__global__ void init_kernel(const float* __restrict__ w, float* __restrict__ wn,
                            int* __restrict__ counts, u64* __restrict__ keys,
                            _Float16* __restrict__ wG) {
    int k = blockIdx.x;
    int lane = threadIdx.x;  // 64
    float4 v = *(const float4*)(w + (size_t)k * DIM + lane * 4);
    float vals[4] = {v.x, v.y, v.z, v.w};

    int q8  = k >> 7;            // code eighth
    int row = k & 127;
    int d0  = lane * 4;          // 4 consecutive d stay in one 16-B swizzle block
    int dt  = d0 >> 5;
    int c0  = d0 & 31;
    int bofs = (2 * c0) ^ ((row & 3) << 4);
    char* dst = (char*)wG + (size_t)(q8 * 8 + dt) * 16384 + row * 64 + bofs;

    half4 hv, lv;
    float s = 0.f;
    #pragma unroll
    for (int e = 0; e < 4; e++) {
        s += vals[e] * vals[e];
        _Float16 h = (_Float16)vals[e];
        hv[e] = h;
        lv[e] = (_Float16)(vals[e] - (float)h);
    }
    *(half4*)dst = hv;
    *(half4*)(dst + 8192) = lv;

    #pragma unroll
    for (int off = 32; off; off >>= 1) s += __shfl_down(s, off);
    if (lane == 0) { wn[k] = s; counts[k] = 0; }
    if (lane < 32) keys[k * 32 + lane] = ~0ull;   // 1024*32 = 32768 keys
}

// ---------------- argmin: fp16-split MFMA distance GEMM + atomicMin merge ----
// dot(z,w) = hi_z*hi_w + hi_z*lo_w + lo_z*hi_w  (lo*lo dropped, err ~1e-5).
// ROUND-11: r10 geometry (64x64 wave tile, 128tok x 128codes block, t_-low
// XCD mapping: FETCH-verified 35 MB) + w staging via global_load_lds DMA
// from the pre-swizzled image, DOUBLE-buffered, issued after B2 so the DMA
// flies under the 48-MFMA block and drains at next iter's B1 (~470 cy later
// -> latency hidden; unlike m97's same-phase drain). z stays in LDS ZS=40
// (r10-verbatim serial staging between B1/B2).
// Why: r4/r10 budget says LDS op count is the binding pipe (r4 23us, r10
// 30.7us lifetime vs MFMA 24.8). DMA removes all w ds_writes + staging VALU:
// 36 -> 20 ops/thread/chunk, lifetime LDS ~20.5us -> MFMA-dominant.
// LDS 53248 B, ~132 unified regs -> 3 blocks/CU (12 waves), bounds(256,3).
__global__ __launch_bounds__(256, 3) void argmin_kernel(
    const float* __restrict__ z, const _Float16* __restrict__ wG,
    const float* __restrict__ wn, u64* __restrict__ keys)
{
    constexpr int ZS = 40;   // z halves per row (80 B, 16-B aligned)
    __shared__ _Float16 zhi[128 * ZS], zlo[128 * ZS];
    __shared__ __attribute__((aligned(16))) char wbuf[2][16384];  // hi 8K | lo 8K

    const int tid  = threadIdx.x;
    const int lane = tid & 63;
    const int wid  = tid >> 6;          // 0..3
    const int wm   = wid >> 1;          // token half (64)
    const int wq   = wid & 1;           // code half (64)
    const int t_   = blockIdx.x & 255;  // token tile (LOW bits: XCD locality, r10-verified)
    const int q8   = blockIdx.x >> 8;   // code eighth 0..7
    const int tok0  = t_ * 128;
    const int kbase = q8 * 128;

    // ||w||^2 for this thread's 4 epilogue columns -> registers
    float wnr[4];
    #pragma unroll
    for (int j = 0; j < 4; j++)
        wnr[j] = wn[kbase + wq * 64 + j * 16 + (lane & 15)];

    floatx4 acc[4][4];
    #pragma unroll
    for (int i = 0; i < 4; i++)
        #pragma unroll
        for (int j = 0; j < 4; j++)
            acc[i][j] = (floatx4){0.f, 0.f, 0.f, 0.f};

    const int r0 = tid >> 2;   // z staging row (0..63)
    const int g0 = tid & 3;    // 8-half group within 32-chunk
    const int kg = lane >> 4;  // k-group 0..3

    // B-frag read: row rB = wq*64 + j*16 + (lane&15); rB&3 == lane&3
    const int rb = (wq * 64 + (lane & 15)) * 64 + ((kg * 16) ^ ((lane & 3) << 4));

    // w DMA: this wave copies bytes [wid*4096, +4096) of the 16 KB chunk
    const char* wGq = (const char*)wG + (size_t)q8 * (8 * 16384) + wid * 4096 + lane * 16;

    // prologue: issue DMA for chunk 0 -> wbuf[0]
    #pragma unroll
    for (int c = 0; c < 4; c++)
        glds16(wGq + c * 1024, &wbuf[0][wid * 4096 + c * 1024]);

    for (int dt = 0; dt < 8; ++dt) {
        const int cur = dt & 1;
        const int d0 = dt * 32;
        __syncthreads();   // B1: drains w DMA(dt); prev MFMA's LDS reads done

        // stage z chunk (128 tok x 32 d): fp32 -> (hi,lo) fp16  [r10-verbatim]
        #pragma unroll
        for (int s = 0; s < 2; s++) {
            int t = r0 + s * 64;
            const float* p = z + (size_t)(tok0 + t) * DIM + d0 + g0 * 8;
            float4 a = *(const float4*)p;
            float4 b = *(const float4*)(p + 4);
            float vals[8] = {a.x, a.y, a.z, a.w, b.x, b.y, b.z, b.w};
            half8 hv, lv;
            #pragma unroll
            for (int e = 0; e < 8; e++) {
                _Float16 h = (_Float16)vals[e];
                hv[e] = h;
                lv[e] = (_Float16)(vals[e] - (float)h);
            }
            *(half8*)&zhi[t * ZS + g0 * 8] = hv;
            *(half8*)&zlo[t * ZS + g0 * 8] = lv;
        }
        __syncthreads();   // B2: z(dt) visible

        // issue w DMA(dt+1) -> other buffer; flies under the MFMA block,
        // drained at next iteration's B1 (~470 cy later).
        if (dt < 7) {
            const char* src = wGq + (dt + 1) * 16384;
            char* ldst = &wbuf[cur ^ 1][wid * 4096];
            #pragma unroll
            for (int c = 0; c < 4; c++)
                glds16(src + c * 1024, ldst + c * 1024);
        }

        // fragments: A[m=lane&15][k=kg*8+e], B[k][n=lane&15]
        const int koff = kg * 8;
        half8 ah[4], al[4];
        #pragma unroll
        for (int i = 0; i < 4; i++) {
            int off = (wm * 64 + i * 16 + (lane & 15)) * ZS + koff;
            ah[i] = *(const half8*)&zhi[off];
            al[i] = *(const half8*)&zlo[off];
        }
        __builtin_amdgcn_s_setprio(1);   // T5: favor MFMA-phase waves
        #pragma unroll
        for (int j = 0; j < 4; j++) {
            const char* pb = &wbuf[cur][rb + j * 1024];
            half8 bh = *(const half8*)pb;
            half8 bl = *(const half8*)(pb + 8192);
            #pragma unroll
            for (int i = 0; i < 4; i++) {
                acc[i][j] = __builtin_amdgcn_mfma_f32_16x16x32_f16(ah[i], bh, acc[i][j], 0, 0, 0);
                acc[i][j] = __builtin_amdgcn_mfma_f32_16x16x32_f16(ah[i], bl, acc[i][j], 0, 0, 0);
                acc[i][j] = __builtin_amdgcn_mfma_f32_16x16x32_f16(al[i], bh, acc[i][j], 0, 0, 0);
            }
        }
        __builtin_amdgcn_s_setprio(0);
    }

    // epilogue: dist = wn[code] - 2*dot (||z||^2 constant per row).
    // C layout: col(code) = lane&15, row(token) = (lane>>4)*4 + reg.  [r10-verbatim]
    #pragma unroll
    for (int i = 0; i < 4; i++) {
        #pragma unroll
        for (int r = 0; r < 4; r++) {
            float bv = 3.4e38f; int bi = 0;
            #pragma unroll
            for (int j = 0; j < 4; j++) {
                int cl = wq * 64 + j * 16 + (lane & 15);
                float dist = wnr[j] - 2.0f * acc[i][j][r];
                if (dist < bv) { bv = dist; bi = kbase + cl; }
            }
            unsigned uu = __float_as_uint(bv);
            unsigned ss = (uu & 0x80000000u) ? ~uu : (uu | 0x80000000u);
            u64 key = ((u64)ss << 32) | (unsigned)bi;
            #pragma unroll
            for (int m = 1; m < 16; m <<= 1) {
                u64 o = __shfl_xor(key, m);
                if (o < key) key = o;
            }
            if ((lane & 15) == 0) {
                int token = tok0 + wm * 64 + i * 16 + (lane >> 4) * 4 + r;
                atomicMin(&keys[token], key);
            }
        }
    }
}

// ---------------- gather + commitment loss + idx/counts ----------------
// wave (64 lanes) = one token (64 float4). 8192 waves x 4 iters.
// k masked to 10 bits: valid keys always carry code < 1024; converts any
// upstream failure into a clean numeric mismatch instead of a wild gather
// -> memory fault -> dead container.
__global__ void gather_loss_kernel(const float* __restrict__ z,
                                   const float* __restrict__ w,
                                   const u64* __restrict__ keys,
                                   float* __restrict__ zq_out,
                                   float* __restrict__ idxf,
                                   int* __restrict__ counts,
                                   float* __restrict__ partials)
{
    __shared__ float red[4];
    int tid = threadIdx.x;
    int lane = tid & 63;
    int wid = blockIdx.x * 4 + (tid >> 6);   // 0..8191
    float s = 0.0f;
    #pragma unroll
    for (int it = 0; it < 4; it++) {
        int tok = wid + it * 8192;
        u64 key = 0;
        if (lane == 0) key = keys[tok];
        key = __shfl(key, 0);
        int k = (int)(key & (u64)(K_CODES - 1));
        float4 wv = *(const float4*)(w + (size_t)k * DIM + lane * 4);
        float4 zv = *(const float4*)(z + (size_t)tok * DIM + lane * 4);
        *(float4*)(zq_out + (size_t)tok * DIM + lane * 4) = wv;
        float dx = wv.x - zv.x, dy = wv.y - zv.y, dz = wv.z - zv.z, dw = wv.w - zv.w;
        s += dx * dx + dy * dy + dz * dz + dw * dw;
        if (lane == 0) {
            idxf[tok] = (float)k;
            atomicAdd(&counts[k], 1);
        }
    }
    #pragma unroll
    for (int off = 32; off; off >>= 1) s += __shfl_down(s, off);
    if (lane == 0) red[tid >> 6] = s;
    __syncthreads();
    if (tid == 0)
        partials[blockIdx.x] = red[0] + red[1] + red[2] + red[3];
}

// ---------------- perplexity + loss finalize ----------------
__global__ void finalize_kernel(const int* __restrict__ counts,
                                const float* __restrict__ partials,
                                float* __restrict__ loss_out,
                                float* __restrict__ ppl_out)
{
    __shared__ float redE[16], redL[16];
    int tid = threadIdx.x;  // 1024
    float e = (float)counts[tid] * (1.0f / (float)N_TOKENS);
    float t = -e * logf(e + 1e-10f);
    float p = partials[tid] + partials[tid + 1024];
    #pragma unroll
    for (int off = 32; off; off >>= 1) {
        t += __shfl_down(t, off);
        p += __shfl_down(p, off);
    }
    if ((tid & 63) == 0) { redE[tid >> 6] = t; redL[tid >> 6] = p; }
    __syncthreads();
    if (tid == 0) {
        float se = 0.0f, sl = 0.0f;
        #pragma unroll
        for (int i = 0; i < 16; i++) { se += redE[i]; sl += redL[i]; }
        *ppl_out = expf(se);
        *loss_out = BETA * sl / (float)((size_t)N_TOKENS * DIM);
    }
}

extern "C" void kernel_launch(void* const* d_in, const int* in_sizes, int n_in,
                              void* d_out, int out_size, void* d_ws, size_t ws_size,
                              hipStream_t stream) {
    const float* z = (const float*)d_in[0];
    const float* w = (const float*)d_in[1];
    float* out = (float*)d_out;

    // d_out layout (float): [0]=loss, [1..NT*D]=z_q_st, [..]=indices(float), [last]=perplexity
    float* loss_out = out;
    float* zq_out   = out + 1;
    float* idxf     = out + 1 + (size_t)N_TOKENS * DIM;
    float* ppl_out  = out + (out_size - 1);

    // ws layout: wn f32[1024] | counts i32[1024] | partials f32[2048]
    //            | keys u64[32768] @ byte 16384 | wG image (1 MB) @ 278528
    float* wn       = (float*)d_ws;
    int*   counts   = (int*)d_ws + 1024;
    float* partials = (float*)d_ws + 2048;
    u64*   keys     = (u64*)((char*)d_ws + 16384);
    _Float16* wG    = (_Float16*)((char*)d_ws + 16384 + (size_t)N_TOKENS * 8);

    init_kernel<<<K_CODES, 64, 0, stream>>>(w, wn, counts, keys, wG);
    argmin_kernel<<<8 * 256, 256, 0, stream>>>(z, wG, wn, keys);
    gather_loss_kernel<<<2048, 256, 0, stream>>>(z, w, keys, zq_out, idxf, counts, partials);
    finalize_kernel<<<1, 1024, 0, stream>>>(counts, partials, loss_out, ppl_out);
}